// Round 1
// baseline (8103.902 us; speedup 1.0000x reference)
//
#include <hip/hip_runtime.h>
#include <hip/hip_bf16.h>

#define SEQ_LEN 48
#define HID     96
#define G3      288
#define NBATCH  131072

__device__ __forceinline__ float fast_rcp(float x) { return __builtin_amdgcn_rcpf(x); }
__device__ __forceinline__ float sigmoid_(float x) { return fast_rcp(1.0f + __expf(-x)); }
__device__ __forceinline__ float tanh_(float x) {
    float a = fabsf(x);
    float e = __expf(2.0f * a);                 // may overflow to +inf: rcp(inf)=0 -> t=1, safe
    float t = 1.0f - 2.0f * fast_rcp(e + 1.0f);
    return copysignf(t, x);
}

// Fold the (linear) embedding path into the GRU input weights:
//   Wxe = W_ih @ W_emb  (288x3),  bx = W_ih @ b_emb + b_ih  (288)
// ws layout (floats): [0..863] Wxe row-major, [864..1055] bsum_rz = bx+b_hh (r,z parts),
//                     [1056..1151] bxn (n part of bx), [1152..1247] bhhn (n part of b_hh)
__global__ void fold_weights(const float* __restrict__ W_emb, const float* __restrict__ b_emb,
                             const float* __restrict__ W_ih,  const float* __restrict__ b_ih,
                             const float* __restrict__ b_hh,  float* __restrict__ ws)
{
    int j = blockIdx.x * blockDim.x + threadIdx.x;
    if (j >= G3) return;
    float w0 = 0.f, w1 = 0.f, w2 = 0.f, bx = b_ih[j];
    for (int e = 0; e < 32; e++) {
        float w = W_ih[j * 32 + e];
        w0 += w * W_emb[e * 3 + 0];
        w1 += w * W_emb[e * 3 + 1];
        w2 += w * W_emb[e * 3 + 2];
        bx += w * b_emb[e];
    }
    ws[3 * j + 0] = w0; ws[3 * j + 1] = w1; ws[3 * j + 2] = w2;
    if (j < 192) ws[864 + j] = bx + b_hh[j];
    else { ws[1056 + j - 192] = bx; ws[1152 + j - 192] = b_hh[j]; }
}

// One thread = one batch row. h[96] lives in VGPRs (all accesses const-indexed via
// unrolled k-loops). The runtime-indexed accesses (h[j] in gate update, h_new[j] store)
// go through a per-lane LDS row (bf16). 1-wave blocks: no __syncthreads needed.
__global__ __launch_bounds__(64, 2)
void gru_main(const float* __restrict__ last_pos, const float* __restrict__ past,
              const float* __restrict__ fut,      const float* __restrict__ W_hh,
              const float* __restrict__ W_out,    const float* __restrict__ b_out,
              const float* __restrict__ ws,       float* __restrict__ out)
{
    __shared__ __hip_bfloat16 hnl[64][98];   // 98*2B = 49-dword lane stride -> conflict-free
    const int lane = threadIdx.x;
    const int row  = blockIdx.x * 64 + lane;

    // h0 = [past | future]; round through bf16 so regs == LDS copy exactly
    #pragma unroll
    for (int k = 0; k < 48; k++) hnl[lane][k]      = __float2bfloat16(past[(size_t)row * 48 + k]);
    #pragma unroll
    for (int k = 0; k < 48; k++) hnl[lane][48 + k] = __float2bfloat16(fut[(size_t)row * 48 + k]);

    float h[HID];
    #pragma unroll
    for (int k = 0; k < HID; k++) h[k] = __bfloat162float(hnl[lane][k]);

    float p0 = last_pos[(size_t)row * 3 + 0];
    float p1 = last_pos[(size_t)row * 3 + 1];
    float p2 = last_pos[(size_t)row * 3 + 2];

    const float* __restrict__ Wxe  = ws;
    const float* __restrict__ bsum = ws + 864;
    const float* __restrict__ bxn  = ws + 1056;
    const float* __restrict__ bhhn = ws + 1152;

    for (int s = 0; s < SEQ_LEN; s++) {
        #pragma unroll 1
        for (int j = 0; j < HID; j++) {
            float sr  = bsum[j]      + p0 * Wxe[3 * j + 0]        + p1 * Wxe[3 * j + 1]        + p2 * Wxe[3 * j + 2];
            float sz  = bsum[96 + j] + p0 * Wxe[3 * (96 + j) + 0] + p1 * Wxe[3 * (96 + j) + 1] + p2 * Wxe[3 * (96 + j) + 2];
            float gxn = bxn[j]       + p0 * Wxe[3 * (192 + j) + 0]+ p1 * Wxe[3 * (192 + j) + 1]+ p2 * Wxe[3 * (192 + j) + 2];
            float sn  = bhhn[j];
            const float* __restrict__ wr = W_hh + j * HID;   // r row; z row = +9216, n row = +18432
            #pragma unroll
            for (int k = 0; k < HID; k++) {
                float hk = h[k];
                sr = fmaf(wr[k],         hk, sr);
                sz = fmaf(wr[k + 9216],  hk, sz);
                sn = fmaf(wr[k + 18432], hk, sn);
            }
            float r  = sigmoid_(sr);
            float z  = sigmoid_(sz);
            float n  = tanh_(fmaf(r, sn, gxn));
            float hj = __bfloat162float(hnl[lane][j]);       // old h[j], runtime idx via LDS
            float hv = fmaf(z, hj - n, n);                   // (1-z)*n + z*h
            hnl[lane][j] = __float2bfloat16(hv);
        }
        // pull h_new back into registers (const-indexed)
        #pragma unroll
        for (int k = 0; k < HID; k++) h[k] = __bfloat162float(hnl[lane][k]);

        // rel_pos = h_new @ W_out^T + b_out ; also the next step's p
        float q0 = b_out[0], q1 = b_out[1], q2 = b_out[2];
        #pragma unroll
        for (int k = 0; k < HID; k++) {
            float hk = h[k];
            q0 = fmaf(W_out[k],       hk, q0);
            q1 = fmaf(W_out[96 + k],  hk, q1);
            q2 = fmaf(W_out[192 + k], hk, q2);
        }
        float* o = out + ((size_t)s * NBATCH + row) * 3;
        o[0] = q0; o[1] = q1; o[2] = q2;
        p0 = q0; p1 = q1; p2 = q2;
    }
}

extern "C" void kernel_launch(void* const* d_in, const int* in_sizes, int n_in,
                              void* d_out, int out_size, void* d_ws, size_t ws_size,
                              hipStream_t stream)
{
    const float* last_pos = (const float*)d_in[0];
    const float* past     = (const float*)d_in[1];
    const float* fut      = (const float*)d_in[2];
    const float* W_emb    = (const float*)d_in[3];
    const float* b_emb    = (const float*)d_in[4];
    const float* W_ih     = (const float*)d_in[5];
    const float* W_hh     = (const float*)d_in[6];
    const float* b_ih     = (const float*)d_in[7];
    const float* b_hh     = (const float*)d_in[8];
    const float* W_out    = (const float*)d_in[9];
    const float* b_out    = (const float*)d_in[10];
    float* out = (float*)d_out;
    float* ws  = (float*)d_ws;

    hipLaunchKernelGGL(fold_weights, dim3(5), dim3(64), 0, stream,
                       W_emb, b_emb, W_ih, b_ih, b_hh, ws);
    hipLaunchKernelGGL(gru_main, dim3(NBATCH / 64), dim3(64), 0, stream,
                       last_pos, past, fut, W_hh, W_out, b_out, ws, out);
}

// Round 2
// 7716.130 us; speedup vs baseline: 1.0503x; 1.0503x over previous
//
#include <hip/hip_runtime.h>
#include <hip/hip_bf16.h>

#define SEQ_LEN 48
#define HID     96
#define NB      131072
#define MROWS   304               // 288 gate rows + 3 W_out rows + 13 zero pad
#define ABYTES  (MROWS*HID*2)     // 58368 B of bf16 A-fragments
#define COEF_OFF_F (ABYTES/4)     // float index 14592 (byte 58368)
#define COEF_FLOATS (96*16)       // 1536 floats
#define BOUT_OFF_F (COEF_OFF_F + COEF_FLOATS)  // float idx 16128 (byte 64512)

typedef __attribute__((ext_vector_type(4))) float f32x4;
typedef __attribute__((ext_vector_type(8))) __bf16 bf16x8;
typedef unsigned int uint;
typedef unsigned short ushort;

__device__ __forceinline__ float sigm(float x) {
    return __builtin_amdgcn_rcpf(1.f + __expf(-x));     // x->+inf: 1 ; x->-inf: 0 (rcp(inf)=0)
}
__device__ __forceinline__ float tanh_(float y) {
    return 1.f - 2.f * __builtin_amdgcn_rcpf(__expf(2.f * y) + 1.f);  // inf-safe both ways
}
__device__ __forceinline__ uint packbf(float a, float b) {
    ushort lo = __builtin_bit_cast(ushort, __float2bfloat16(a));
    ushort hi = __builtin_bit_cast(ushort, __float2bfloat16(b));
    return (uint)lo | ((uint)hi << 16);
}

// ---------------- weight folding: build A-fragment table + epilogue coeffs ----------------
// A rows: 0..95 r: W_hh + Wxe_r@W_out ; 96..191 z: same ; 192..287 n: W_hh only ;
//         288..290: W_out ; 291..303: zero.
// coeff[j][16]: [wn0,wn1,wn2,bxn, bhhn,bsr,bsz,0, wr0,wr1,wr2, wz0,wz1,wz2, 0,0]
__global__ void fold_k(const float* __restrict__ W_emb, const float* __restrict__ b_emb,
                       const float* __restrict__ W_ih,  const float* __restrict__ W_hh,
                       const float* __restrict__ b_ih,  const float* __restrict__ b_hh,
                       const float* __restrict__ W_out, const float* __restrict__ b_out,
                       void* wsv)
{
    ushort* A  = (ushort*)wsv;
    float*  CF = (float*)wsv + COEF_OFF_F;
    float*  BO = (float*)wsv + BOUT_OFF_F;
    int g = blockIdx.x * 64 + threadIdx.x;   // grid 5x64 = 320 threads
    if (g < 3) BO[g] = b_out[g];

    auto wxe_row = [&](int gg, float* w, float& bx) {
        w[0] = w[1] = w[2] = 0.f; bx = b_ih[gg];
        for (int e = 0; e < 32; e++) {
            float wi = W_ih[gg * 32 + e];
            w[0] += wi * W_emb[e * 3 + 0];
            w[1] += wi * W_emb[e * 3 + 1];
            w[2] += wi * W_emb[e * 3 + 2];
            bx   += wi * b_emb[e];
        }
    };

    if (g < MROWS) {
        float w[3] = {0.f, 0.f, 0.f}, bx = 0.f;
        if (g < 192) wxe_row(g, w, bx);
        for (int k = 0; k < HID; k++) {
            float val;
            if      (g < 192) val = W_hh[g * HID + k] + w[0]*W_out[0*HID+k] + w[1]*W_out[1*HID+k] + w[2]*W_out[2*HID+k];
            else if (g < 288) val = W_hh[g * HID + k];
            else if (g < 291) val = W_out[(g - 288) * HID + k];
            else              val = 0.f;
            int t = g >> 4, c = k >> 5, l = (g & 15) | (((k >> 3) & 3) << 4), i = k & 7;
            A[((t * 3 + c) * 64 + l) * 8 + i] = __builtin_bit_cast(ushort, __float2bfloat16(val));
        }
    }
    if (g < 96) {
        int j = g;
        float wn[3], bxn; wxe_row(192 + j, wn, bxn);
        float wr[3], bxr; wxe_row(j,        wr, bxr);
        float wz[3], bxz; wxe_row(96 + j,   wz, bxz);
        float* row = CF + j * 16;
        row[0] = wn[0]; row[1] = wn[1]; row[2] = wn[2]; row[3] = bxn;
        row[4] = b_hh[192 + j];
        row[5] = bxr + b_hh[j]      + wr[0]*b_out[0] + wr[1]*b_out[1] + wr[2]*b_out[2];
        row[6] = bxz + b_hh[96 + j] + wz[0]*b_out[0] + wz[1]*b_out[1] + wz[2]*b_out[2];
        row[7] = 0.f;
        row[8] = wr[0]; row[9] = wr[1]; row[10] = wr[2];
        row[11] = wz[0]; row[12] = wz[1]; row[13] = wz[2];
        row[14] = 0.f; row[15] = 0.f;
    }
}

// ---------------- main GRU kernel: MFMA, swapped orientation D = W @ h^T ----------------
// Wave owns 32 batch cols (2 N-tiles). 4 waves/block. No barriers after staging.
__global__ __launch_bounds__(256, 2)
void gru_mfma(const float* __restrict__ last_pos, const float* __restrict__ past,
              const float* __restrict__ fut, const void* __restrict__ wsv,
              float* __restrict__ out)
{
    __shared__ uint4 sb[4032];                 // 64512 B: A-frags (3648 uint4) + coeff
    const int tid = threadIdx.x;
    const uint4* gsrc = (const uint4*)wsv;
    #pragma unroll
    for (int it = 0; it < 16; ++it) { int idx = tid + it * 256; if (idx < 4032) sb[idx] = gsrc[idx]; }
    __syncthreads();

    const float* CF = (const float*)sb + COEF_OFF_F;
    const float* BOg = (const float*)wsv + BOUT_OFF_F;
    const float bo[3] = {BOg[0], BOg[1], BOg[2]};

    const int lane = tid & 63;
    const int wid  = tid >> 6;
    const int b    = lane & 15;
    const int q    = lane >> 4;
    const int rowbase = blockIdx.x * 128 + wid * 32;

    // ---- h0 (bf16-packed, D-layout: lane holds h[16t+4q+r] for col b) ----
    uint hpk[2][6][2];
    #pragma unroll
    for (int nt = 0; nt < 2; ++nt) {
        int row = rowbase + nt * 16 + b;
        #pragma unroll
        for (int t = 0; t < 6; ++t) {
            const float* src = (t < 3) ? (past + (size_t)row * 48 + t * 16 + q * 4)
                                       : (fut  + (size_t)row * 48 + (t - 3) * 16 + q * 4);
            f32x4 v = *(const f32x4*)src;
            hpk[nt][t][0] = packbf(v[0], v[1]);
            hpk[nt][t][1] = packbf(v[2], v[3]);
        }
    }

    // ---- intra-wave exchange: D-layout hpk -> B-fragments (col=lane&15, k=(lane>>4)*8+i) ----
    const int idxA = 4 * (b | ((((q << 1) + 0) & 3) << 4));   // for elems i<4
    const int idxB = 4 * (b | ((((q << 1) + 1) & 3) << 4));   // for elems i>=4
    uint4 bfu[2][3];
    auto do_exchange = [&]() {
        #pragma unroll
        for (int nt = 0; nt < 2; ++nt)
            #pragma unroll
            for (int c = 0; c < 3; ++c)
                #pragma unroll
                for (int dd = 0; dd < 4; ++dd) {
                    int idx = (dd < 2) ? idxA : idxB;
                    int va = __builtin_amdgcn_ds_bpermute(idx, (int)hpk[nt][2 * c][dd & 1]);
                    int vb = __builtin_amdgcn_ds_bpermute(idx, (int)hpk[nt][2 * c + 1][dd & 1]);
                    bfu[nt][c][dd] = (uint)((lane < 32) ? va : vb);
                }
    };
    do_exchange();

    // ---- p0 ----
    float pc[2][3];
    #pragma unroll
    for (int nt = 0; nt < 2; ++nt) {
        int row = rowbase + nt * 16 + b;
        pc[nt][0] = last_pos[(size_t)row * 3 + 0];
        pc[nt][1] = last_pos[(size_t)row * 3 + 1];
        pc[nt][2] = last_pos[(size_t)row * 3 + 2];
    }

    const f32x4 zero4 = {0.f, 0.f, 0.f, 0.f};
    f32x4 acc[19][2];

    #pragma unroll 1
    for (int s = 0; s < SEQ_LEN; ++s) {
        // ---- GEMM: D[gate, col] = W_aug @ h_s^T ----
        #pragma unroll
        for (int t = 0; t < 19; ++t)
            #pragma unroll
            for (int c = 0; c < 3; ++c) {
                bf16x8 a = __builtin_bit_cast(bf16x8, sb[(t * 3 + c) * 64 + lane]);
                #pragma unroll
                for (int nt = 0; nt < 2; ++nt) {
                    bf16x8 bb = __builtin_bit_cast(bf16x8, bfu[nt][c]);
                    acc[t][nt] = __builtin_amdgcn_mfma_f32_16x16x32_bf16(
                        a, bb, (c == 0) ? zero4 : acc[t][nt], 0, 0, 0);
                }
            }

        // ---- out rows (tile 18): rel_pos_{s-1}; broadcast to all lanes as p_s ----
        float d0[2][3];
        #pragma unroll
        for (int nt = 0; nt < 2; ++nt)
            #pragma unroll
            for (int o = 0; o < 3; ++o) {
                float po = acc[18][nt][o] + bo[o];
                float pb = __builtin_bit_cast(float,
                            __builtin_amdgcn_ds_bpermute(4 * b, __builtin_bit_cast(int, po)));
                if (s > 0) {
                    if (q == 0) {
                        int row = rowbase + nt * 16 + b;
                        out[((size_t)(s - 1) * NB + row) * 3 + o] = po;
                    }
                    pc[nt][o] = pb;
                } else {
                    d0[nt][o] = pc[nt][o] - pb;    // p0 - p~0 (step-0 folding correction)
                }
            }

        // ---- epilogue: gate math (lane-local), h_new ----
        #pragma unroll
        for (int t = 0; t < 6; ++t) {
            f32x4 ca[4], cb[4], c2[4], c3[4];
            #pragma unroll
            for (int r = 0; r < 4; ++r) {
                int j = 16 * t + 4 * q + r;
                ca[r] = *(const f32x4*)(CF + j * 16);
                cb[r] = *(const f32x4*)(CF + j * 16 + 4);
                if (s == 0) {
                    c2[r] = *(const f32x4*)(CF + j * 16 + 8);
                    c3[r] = *(const f32x4*)(CF + j * 16 + 12);
                }
            }
            #pragma unroll
            for (int nt = 0; nt < 2; ++nt) {
                uint np0 = 0, np1 = 0;
                #pragma unroll
                for (int r = 0; r < 4; ++r) {
                    float sr  = acc[t][nt][r]      + cb[r][1];
                    float sz  = acc[6 + t][nt][r]  + cb[r][2];
                    float ghn = acc[12 + t][nt][r] + cb[r][0];
                    float gxn = ca[r][3] + pc[nt][0]*ca[r][0] + pc[nt][1]*ca[r][1] + pc[nt][2]*ca[r][2];
                    if (s == 0) {
                        sr += d0[nt][0]*c2[r][0] + d0[nt][1]*c2[r][1] + d0[nt][2]*c2[r][2];
                        sz += d0[nt][0]*c2[r][3] + d0[nt][1]*c3[r][0] + d0[nt][2]*c3[r][1];
                    }
                    float rg = sigm(sr);
                    float zg = sigm(sz);
                    float ng = tanh_(gxn + rg * ghn);
                    uint pk = hpk[nt][t][r >> 1];
                    float hold = __builtin_bit_cast(float, (r & 1) ? (pk & 0xffff0000u) : (pk << 16));
                    float hv = ng + zg * (hold - ng);
                    ushort hb = __builtin_bit_cast(ushort, __float2bfloat16(hv));
                    if      (r == 0) np0 = hb;
                    else if (r == 1) np0 |= (uint)hb << 16;
                    else if (r == 2) np1 = hb;
                    else             np1 |= (uint)hb << 16;
                }
                hpk[nt][t][0] = np0;
                hpk[nt][t][1] = np1;
            }
        }

        do_exchange();   // h_{s+1} -> B-fragments (also feeds the final mini-GEMM)
    }

    // ---- final: rel_pos_47 = h_48 @ W_out^T + b_out (tile 18 only) ----
    f32x4 f18[2];
    #pragma unroll
    for (int c = 0; c < 3; ++c) {
        bf16x8 a = __builtin_bit_cast(bf16x8, sb[(18 * 3 + c) * 64 + lane]);
        #pragma unroll
        for (int nt = 0; nt < 2; ++nt) {
            bf16x8 bb = __builtin_bit_cast(bf16x8, bfu[nt][c]);
            f18[nt] = __builtin_amdgcn_mfma_f32_16x16x32_bf16(a, bb, (c == 0) ? zero4 : f18[nt], 0, 0, 0);
        }
    }
    if (q == 0) {
        #pragma unroll
        for (int nt = 0; nt < 2; ++nt) {
            int row = rowbase + nt * 16 + b;
            #pragma unroll
            for (int o = 0; o < 3; ++o)
                out[((size_t)47 * NB + row) * 3 + o] = f18[nt][o] + bo[o];
        }
    }
}

extern "C" void kernel_launch(void* const* d_in, const int* in_sizes, int n_in,
                              void* d_out, int out_size, void* d_ws, size_t ws_size,
                              hipStream_t stream)
{
    const float* last_pos = (const float*)d_in[0];
    const float* past     = (const float*)d_in[1];
    const float* fut      = (const float*)d_in[2];
    const float* W_emb    = (const float*)d_in[3];
    const float* b_emb    = (const float*)d_in[4];
    const float* W_ih     = (const float*)d_in[5];
    const float* W_hh     = (const float*)d_in[6];
    const float* b_ih     = (const float*)d_in[7];
    const float* b_hh     = (const float*)d_in[8];
    const float* W_out    = (const float*)d_in[9];
    const float* b_out    = (const float*)d_in[10];
    float* out = (float*)d_out;

    hipLaunchKernelGGL(fold_k, dim3(5), dim3(64), 0, stream,
                       W_emb, b_emb, W_ih, W_hh, b_ih, b_hh, W_out, b_out, d_ws);
    hipLaunchKernelGGL(gru_mfma, dim3(NB / 128), dim3(256), 0, stream,
                       last_pos, past, fut, d_ws, out);
}

// Round 5
// 4773.417 us; speedup vs baseline: 1.6977x; 1.6165x over previous
//
#include <hip/hip_runtime.h>
#include <hip/hip_bf16.h>

#define SEQ_LEN 48
#define HID     96
#define NB      131072
#define MROWS   304                    // 288 gate rows + 3 W_out rows + 13 zero pad
#define ABYTES  (MROWS*HID*2)          // 58368 B of bf16 A-fragments
#define COEF_OFF_F (ABYTES/4)          // float index 14592
#define COEF_FLOATS (96*16)            // stride-16 rows, UNSWIZZLED (injective, round-2 layout)
#define BOUT_OFF_F (COEF_OFF_F + COEF_FLOATS)   // float idx 16128
#define LDS_U4  ((ABYTES + COEF_FLOATS*4)/16)   // 4032 uint4 = 64512 B

typedef __attribute__((ext_vector_type(4))) float f32x4;
typedef __attribute__((ext_vector_type(8))) __bf16 bf16x8;
typedef unsigned int uint;
typedef unsigned short ushort;

__device__ __forceinline__ float sigm(float x) {
    return __builtin_amdgcn_rcpf(1.f + __expf(-x));     // inf-safe
}
__device__ __forceinline__ float tanh_(float y) {
    return 1.f - 2.f * __builtin_amdgcn_rcpf(__expf(2.f * y) + 1.f);  // inf-safe
}
__device__ __forceinline__ uint packbf(float a, float b) {
    ushort lo = __builtin_bit_cast(ushort, __float2bfloat16(a));
    ushort hi = __builtin_bit_cast(ushort, __float2bfloat16(b));
    return (uint)lo | ((uint)hi << 16);
}

// ---------------- weight folding (round-2 coeff layout: stride 16, no swizzle) ----------
__global__ void fold_k(const float* __restrict__ W_emb, const float* __restrict__ b_emb,
                       const float* __restrict__ W_ih,  const float* __restrict__ W_hh,
                       const float* __restrict__ b_ih,  const float* __restrict__ b_hh,
                       const float* __restrict__ W_out, const float* __restrict__ b_out,
                       void* wsv)
{
    ushort* A  = (ushort*)wsv;
    float*  CF = (float*)wsv + COEF_OFF_F;
    float*  BO = (float*)wsv + BOUT_OFF_F;
    int g = blockIdx.x * 64 + threadIdx.x;
    if (g < 3) BO[g] = b_out[g];

    auto wxe_row = [&](int gg, float* w, float& bx) {
        w[0] = w[1] = w[2] = 0.f; bx = b_ih[gg];
        for (int e = 0; e < 32; e++) {
            float wi = W_ih[gg * 32 + e];
            w[0] += wi * W_emb[e * 3 + 0];
            w[1] += wi * W_emb[e * 3 + 1];
            w[2] += wi * W_emb[e * 3 + 2];
            bx   += wi * b_emb[e];
        }
    };

    if (g < MROWS) {
        float w[3] = {0.f, 0.f, 0.f}, bx = 0.f;
        if (g < 192) wxe_row(g, w, bx);
        for (int k = 0; k < HID; k++) {
            float val;
            if      (g < 192) val = W_hh[g * HID + k] + w[0]*W_out[0*HID+k] + w[1]*W_out[1*HID+k] + w[2]*W_out[2*HID+k];
            else if (g < 288) val = W_hh[g * HID + k];
            else if (g < 291) val = W_out[(g - 288) * HID + k];
            else              val = 0.f;
            int t = g >> 4, c = k >> 5, l = (g & 15) | (((k >> 3) & 3) << 4), i = k & 7;
            A[((t * 3 + c) * 64 + l) * 8 + i] = __builtin_bit_cast(ushort, __float2bfloat16(val));
        }
    }
    if (g < 96) {
        int j = g;
        float wn[3], bxn; wxe_row(192 + j, wn, bxn);
        float wr[3], bxr; wxe_row(j,        wr, bxr);
        float wz[3], bxz; wxe_row(96 + j,   wz, bxz);
        float* row = CF + j * 16;                     // stride 16, injective
        row[0] = wn[0]; row[1] = wn[1]; row[2] = wn[2]; row[3] = bxn;
        row[4] = b_hh[192 + j];
        row[5] = bxr + b_hh[j]      + wr[0]*b_out[0] + wr[1]*b_out[1] + wr[2]*b_out[2];
        row[6] = bxz + b_hh[96 + j] + wz[0]*b_out[0] + wz[1]*b_out[1] + wz[2]*b_out[2];
        row[7] = 0.f;
        row[8] = wr[0]; row[9] = wr[1]; row[10] = wr[2];
        row[11] = wz[0]; row[12] = wz[1]; row[13] = wz[2];
        row[14] = 0.f; row[15] = 0.f;
    }
}

// ---------------- main kernel: grouped GEMM+epilogue to keep accumulators short-lived ----
__global__ __launch_bounds__(256, 2)
void gru_mfma(const float* __restrict__ last_pos, const float* __restrict__ past,
              const float* __restrict__ fut, const void* __restrict__ wsv,
              float* __restrict__ out)
{
    __shared__ uint4 sb[LDS_U4];
    const int tid = threadIdx.x;
    const uint4* gsrc = (const uint4*)wsv;
    #pragma unroll
    for (int it = 0; it < 16; ++it) { int idx = tid + it * 256; if (idx < LDS_U4) sb[idx] = gsrc[idx]; }
    __syncthreads();

    const float* CF  = (const float*)sb + COEF_OFF_F;
    const float* BOg = (const float*)wsv + BOUT_OFF_F;
    const float bo[3] = {BOg[0], BOg[1], BOg[2]};

    const int lane = tid & 63;
    const int wid  = tid >> 6;
    const int b    = lane & 15;
    const int q    = lane >> 4;
    const int rowbase = blockIdx.x * 128 + wid * 32;

    // ---- h0 (bf16-packed, D-layout: lane holds h[16t+4q+r] for col b) ----
    uint hpk[2][6][2];
    #pragma unroll
    for (int nt = 0; nt < 2; ++nt) {
        int row = rowbase + nt * 16 + b;
        #pragma unroll
        for (int t = 0; t < 6; ++t) {
            const float* src = (t < 3) ? (past + (size_t)row * 48 + t * 16 + q * 4)
                                       : (fut  + (size_t)row * 48 + (t - 3) * 16 + q * 4);
            f32x4 v = *(const f32x4*)src;
            hpk[nt][t][0] = packbf(v[0], v[1]);
            hpk[nt][t][1] = packbf(v[2], v[3]);
        }
    }

    // ---- intra-wave exchange: D-layout hpk -> B-fragments ----
    const int idxA = 4 * (b | ((((q << 1) + 0) & 3) << 4));
    const int idxB = 4 * (b | ((((q << 1) + 1) & 3) << 4));
    uint4 bfu[2][3];
    auto do_exchange = [&]() {
        #pragma unroll
        for (int nt = 0; nt < 2; ++nt)
            #pragma unroll
            for (int c = 0; c < 3; ++c)
                #pragma unroll
                for (int dd = 0; dd < 4; ++dd) {
                    int idx = (dd < 2) ? idxA : idxB;
                    int va = __builtin_amdgcn_ds_bpermute(idx, (int)hpk[nt][2 * c][dd & 1]);
                    int vb = __builtin_amdgcn_ds_bpermute(idx, (int)hpk[nt][2 * c + 1][dd & 1]);
                    bfu[nt][c][dd] = (uint)((lane < 32) ? va : vb);
                }
    };
    do_exchange();

    // ---- p0 ----
    float pc[2][3];
    #pragma unroll
    for (int nt = 0; nt < 2; ++nt) {
        int row = rowbase + nt * 16 + b;
        pc[nt][0] = last_pos[(size_t)row * 3 + 0];
        pc[nt][1] = last_pos[(size_t)row * 3 + 1];
        pc[nt][2] = last_pos[(size_t)row * 3 + 2];
    }

    const f32x4 zero4 = {0.f, 0.f, 0.f, 0.f};

    #pragma unroll 1
    for (int s = 0; s < SEQ_LEN; ++s) {
        // ---- tile 18 first: rel_pos_{s-1} -> p_s (needed by epilogue below) ----
        f32x4 a18[2];
        #pragma unroll
        for (int c = 0; c < 3; ++c) {
            bf16x8 a = __builtin_bit_cast(bf16x8, sb[(18 * 3 + c) * 64 + lane]);
            #pragma unroll
            for (int nt = 0; nt < 2; ++nt) {
                bf16x8 bb = __builtin_bit_cast(bf16x8, bfu[nt][c]);
                a18[nt] = __builtin_amdgcn_mfma_f32_16x16x32_bf16(a, bb, (c == 0) ? zero4 : a18[nt], 0, 0, 0);
            }
        }
        float d0[2][3];
        #pragma unroll
        for (int nt = 0; nt < 2; ++nt)
            #pragma unroll
            for (int o = 0; o < 3; ++o) {
                float po = a18[nt][o] + bo[o];
                float pb = __builtin_bit_cast(float,
                            __builtin_amdgcn_ds_bpermute(4 * b, __builtin_bit_cast(int, po)));
                if (s > 0) {
                    if (q == 0) {
                        int row = rowbase + nt * 16 + b;
                        out[((size_t)(s - 1) * NB + row) * 3 + o] = po;
                    }
                    pc[nt][o] = pb;
                } else {
                    d0[nt][o] = pc[nt][o] - pb;    // step-0 folding correction
                }
            }
        __builtin_amdgcn_sched_barrier(0);

        // ---- 6 groups: {r,z,n} GEMM for rows 16t..16t+15, then immediate epilogue ----
        #pragma unroll
        for (int t = 0; t < 6; ++t) {
            f32x4 aR[2], aZ[2], aN[2];
            #pragma unroll
            for (int c = 0; c < 3; ++c) {
                bf16x8 fr = __builtin_bit_cast(bf16x8, sb[((t)      * 3 + c) * 64 + lane]);
                bf16x8 fz = __builtin_bit_cast(bf16x8, sb[((6 + t)  * 3 + c) * 64 + lane]);
                bf16x8 fn = __builtin_bit_cast(bf16x8, sb[((12 + t) * 3 + c) * 64 + lane]);
                #pragma unroll
                for (int nt = 0; nt < 2; ++nt) {
                    bf16x8 bb = __builtin_bit_cast(bf16x8, bfu[nt][c]);
                    aR[nt] = __builtin_amdgcn_mfma_f32_16x16x32_bf16(fr, bb, (c == 0) ? zero4 : aR[nt], 0, 0, 0);
                    aZ[nt] = __builtin_amdgcn_mfma_f32_16x16x32_bf16(fz, bb, (c == 0) ? zero4 : aZ[nt], 0, 0, 0);
                    aN[nt] = __builtin_amdgcn_mfma_f32_16x16x32_bf16(fn, bb, (c == 0) ? zero4 : aN[nt], 0, 0, 0);
                }
            }
            const float* cbase = CF + (16 * t + 4 * q) * 16;   // unswizzled stride-16 rows
            f32x4 ca[4], cb[4], c2[4], c3[4];
            #pragma unroll
            for (int r = 0; r < 4; ++r) {
                ca[r] = *(const f32x4*)(cbase + 16 * r);
                cb[r] = *(const f32x4*)(cbase + 16 * r + 4);
                if (s == 0) {
                    c2[r] = *(const f32x4*)(cbase + 16 * r + 8);
                    c3[r] = *(const f32x4*)(cbase + 16 * r + 12);
                }
            }
            #pragma unroll
            for (int nt = 0; nt < 2; ++nt) {
                uint np0 = 0, np1 = 0;
                #pragma unroll
                for (int r = 0; r < 4; ++r) {
                    float sr  = aR[nt][r] + cb[r][1];
                    float sz  = aZ[nt][r] + cb[r][2];
                    float ghn = aN[nt][r] + cb[r][0];
                    float gxn = ca[r][3] + pc[nt][0]*ca[r][0] + pc[nt][1]*ca[r][1] + pc[nt][2]*ca[r][2];
                    if (s == 0) {
                        sr += d0[nt][0]*c2[r][0] + d0[nt][1]*c2[r][1] + d0[nt][2]*c2[r][2];
                        sz += d0[nt][0]*c2[r][3] + d0[nt][1]*c3[r][0] + d0[nt][2]*c3[r][1];
                    }
                    float rg = sigm(sr);
                    float zg = sigm(sz);
                    float ng = tanh_(gxn + rg * ghn);
                    uint pk = hpk[nt][t][r >> 1];
                    float hold = __builtin_bit_cast(float, (r & 1) ? (pk & 0xffff0000u) : (pk << 16));
                    float hv = ng + zg * (hold - ng);
                    ushort hb = __builtin_bit_cast(ushort, __float2bfloat16(hv));
                    if      (r == 0) np0 = hb;
                    else if (r == 1) np0 |= (uint)hb << 16;
                    else if (r == 2) np1 = hb;
                    else             np1 |= (uint)hb << 16;
                }
                hpk[nt][t][0] = np0;
                hpk[nt][t][1] = np1;
            }
            __builtin_amdgcn_sched_barrier(0);
        }

        do_exchange();   // h_{s+1} -> B-fragments
    }

    // ---- final: rel_pos_47 = h_48 @ W_out^T + b_out ----
    f32x4 f18[2];
    #pragma unroll
    for (int c = 0; c < 3; ++c) {
        bf16x8 a = __builtin_bit_cast(bf16x8, sb[(18 * 3 + c) * 64 + lane]);
        #pragma unroll
        for (int nt = 0; nt < 2; ++nt) {
            bf16x8 bb = __builtin_bit_cast(bf16x8, bfu[nt][c]);
            f18[nt] = __builtin_amdgcn_mfma_f32_16x16x32_bf16(a, bb, (c == 0) ? zero4 : f18[nt], 0, 0, 0);
        }
    }
    if (q == 0) {
        #pragma unroll
        for (int nt = 0; nt < 2; ++nt) {
            int row = rowbase + nt * 16 + b;
            #pragma unroll
            for (int o = 0; o < 3; ++o)
                out[((size_t)47 * NB + row) * 3 + o] = f18[nt][o] + bo[o];
        }
    }
}

extern "C" void kernel_launch(void* const* d_in, const int* in_sizes, int n_in,
                              void* d_out, int out_size, void* d_ws, size_t ws_size,
                              hipStream_t stream)
{
    const float* last_pos = (const float*)d_in[0];
    const float* past     = (const float*)d_in[1];
    const float* fut      = (const float*)d_in[2];
    const float* W_emb    = (const float*)d_in[3];
    const float* b_emb    = (const float*)d_in[4];
    const float* W_ih     = (const float*)d_in[5];
    const float* W_hh     = (const float*)d_in[6];
    const float* b_ih     = (const float*)d_in[7];
    const float* b_hh     = (const float*)d_in[8];
    const float* W_out    = (const float*)d_in[9];
    const float* b_out    = (const float*)d_in[10];
    float* out = (float*)d_out;

    hipLaunchKernelGGL(fold_k, dim3(5), dim3(64), 0, stream,
                       W_emb, b_emb, W_ih, W_hh, b_ih, b_hh, W_out, b_out, d_ws);
    hipLaunchKernelGGL(gru_mfma, dim3(NB / 128), dim3(256), 0, stream,
                       last_pos, past, fut, d_ws, out);
}